// Round 6
// baseline (5943.149 us; speedup 1.0000x reference)
//
#include <hip/hip_runtime.h>

typedef _Float16 h4 __attribute__((ext_vector_type(4)));
typedef float f4 __attribute__((ext_vector_type(4)));

#define SEQ_LEN 50
#define HID 64
#define FSTRIDE 68   // final-h LDS row pitch in halves

#if __has_builtin(__builtin_amdgcn_exp2f)
#define EXP2(x) __builtin_amdgcn_exp2f(x)
#else
extern "C" __device__ float __ocml_native_exp2_f32(float);
#define EXP2(x) __ocml_native_exp2_f32(x)
#endif
#define RCP(x) __builtin_amdgcn_rcpf(x)

// verified on this harness in R1/R3/R10 (R10 passed with it unconditional)
#define MFMA16(A,B,C) __builtin_amdgcn_mfma_f32_16x16x16f16(A, B, C, 0, 0, 0)

#define LOG2E  1.442695041f
#define LOG2E2 2.885390082f

// R12: barrier-free register-resident h + LDS-resident weights.
//
// R10 post-mortem: the barrier-free core worked (bank conflicts -60%,
// MfmaUtil 29->41%) but weight fragments in registers cost 192 VGPRs
// (h4 = 2 VGPRs, miscounted as 1); allocator split 128 arch / 128 acc and
// spilled ~100 regs -> WRITE_SIZE 6 MB -> 200 MB of per-step scratch
// drains (scratch reads hit L2, hence FETCH flat) -> 2290 us.
//
// Fix: keep only the kc=0 weight chunk in registers (32 VGPRs); kc=1..3
// and the x-projection fragments live in LDS, staged ONCE as pre-scaled
// f16 MFMA A-fragments. Weights are loop-invariant read-only -> no barrier
// in the t-loop; waves stay fully independent (the R10 core idea).
// LDS frag reads are VOLATILE: without it, LICM hoists 48 loop-invariant
// frag loads into registers and recreates R10's spill.
//
// Fragment identity (HW-verified by R10 passing): for mfma_f32_16x16x16_f16
// D-layout == B-layout (col=lane&15; row/k = 4*(lane>>4)+idx), so the
// activated h4 of unit-quarter dq IS the B-fragment for k-chunk dq of the
// next timestep. A-layout m=col, k=4*quad+j -> frag(tile,kc)[lane] =
// W_hh[n=gi*64+dq*16+col][kc*16+quad*4+j]*scale.
//
// Activation math (R6/R7, verified; verbatim from R10): pre-acts pre-scaled
// (i,f,o: log2e; g: 2log2e, folded into fragments). Cell kept in 2log2e
// domain. Paired rcp both sites. c' clamp 40 keeps paired products finite.
//
// Budget: VGPR ~150 -> __launch_bounds__(256,3) (cap 170), 3 waves/SIMD;
// LDS 45.5 KB -> 3 blocks/CU. Per wave-step: ~64 b64 LDS reads (~450 cyc,
// overlapped), 80 x16 MFMAs, trans 96 inst -> VALU-issue-bound by design.
__global__ __launch_bounds__(256, 3)
void lstm_fused(const float* __restrict__ x,
                const float* __restrict__ W_ih,
                const float* __restrict__ W_hh,
                const float* __restrict__ b_ih,
                const float* __restrict__ b_hh,
                const float* __restrict__ W_fc,
                const float* __restrict__ b_fc,
                float* __restrict__ out)
{
    __shared__ float sXT[SEQ_LEN * 64];  // x transposed [t][seq]; reused as sF
    __shared__ h4    sW[16 * 3 * 64];    // W frags kc=1..3: [(tile*3+kcL)*64+lane]
    __shared__ h4    sX[16 * 64];        // x-proj frags:    [tile*64+lane]

    const int tid  = threadIdx.x;
    const int wave = tid >> 6;
    const int lane = tid & 63;
    const int col  = lane & 15;
    const int quad = lane >> 4;
    const int seqBase = blockIdx.x << 6;     // 64 sequences per block

    // ---- stage x transposed
    for (int i = tid; i < SEQ_LEN * 64; i += 256) {
        const int s = i / SEQ_LEN;
        const int t = i - s * SEQ_LEN;
        sXT[t * 64 + s] = x[(size_t)(seqBase + s) * SEQ_LEN + t];
    }

    // ---- stage W fragments (kc=1..3) into LDS, pre-scaled
    for (int i = tid; i < 16 * 3 * 64; i += 256) {
        const int ln   = i & 63;
        const int rest = i >> 6;        // = tile*3 + kcL
        const int kcL  = rest % 3;      // kc = kcL+1
        const int tile = rest / 3;
        const int gi = tile >> 2, dq = tile & 3;
        const int cl = ln & 15, qd = ln >> 4;
        const int n  = gi * 64 + dq * 16 + cl;
        const float scale = (gi == 2) ? LOG2E2 : LOG2E;
        const float* wp = W_hh + (size_t)n * HID + (kcL + 1) * 16 + qd * 4;
        f4 w = *(const f4*)wp;
        h4 a;
        a[0] = (_Float16)(w[0] * scale);
        a[1] = (_Float16)(w[1] * scale);
        a[2] = (_Float16)(w[2] * scale);
        a[3] = (_Float16)(w[3] * scale);
        sW[i] = a;
    }
    // ---- stage x-projection fragments (nonzero only quad 0, k=0,1)
    for (int i = tid; i < 16 * 64; i += 256) {
        const int ln   = i & 63;
        const int tile = i >> 6;
        const int gi = tile >> 2, dq = tile & 3;
        const int cl = ln & 15, qd = ln >> 4;
        const int n  = gi * 64 + dq * 16 + cl;
        const float scale = (gi == 2) ? LOG2E2 : LOG2E;
        h4 a = {};
        if (qd == 0) {
            a[0] = (_Float16)(W_ih[n] * scale);
            a[1] = (_Float16)((b_ih[n] + b_hh[n]) * scale);
        }
        sX[i] = a;
    }

    // ---- kc=0 weight chunk resident in registers (32 VGPRs)
    h4 Aw0[4][4];
    #pragma unroll
    for (int gi = 0; gi < 4; ++gi) {
        const float scale = (gi == 2) ? LOG2E2 : LOG2E;
        #pragma unroll
        for (int dq = 0; dq < 4; ++dq) {
            const int n = gi * 64 + dq * 16 + col;
            const float* wp = W_hh + (size_t)n * HID + quad * 4;
            f4 w = *(const f4*)wp;
            h4 a;
            a[0] = (_Float16)(w[0] * scale);
            a[1] = (_Float16)(w[1] * scale);
            a[2] = (_Float16)(w[2] * scale);
            a[3] = (_Float16)(w[3] * scale);
            Aw0[gi][dq] = a;
        }
    }

    const f4 z4 = {0.0f, 0.0f, 0.0f, 0.0f};

    h4 hB[4] = {};          // h as ready-made B-fragments (h0 = 0)
    float c[4][4];
    #pragma unroll
    for (int dq = 0; dq < 4; ++dq)
        #pragma unroll
        for (int r = 0; r < 4; ++r) c[dq][r] = 0.0f;

    __syncthreads();        // staging done; the ONLY barrier before epilogue

    for (int t = 0; t < SEQ_LEN; ++t) {
        const float xt = sXT[t * 64 + wave * 16 + col];
        h4 bext = {};
        bext[0] = (_Float16)xt;
        bext[1] = (_Float16)1.0f;

        h4 hN[4];
        #pragma unroll
        for (int dq = 0; dq < 4; ++dq) {
            f4 acc[4];
            #pragma unroll
            for (int gi = 0; gi < 4; ++gi) {
                const int tile = gi * 4 + dq;
                // volatile: keep frag loads inside the loop (see header)
                h4 ax = *(volatile const h4*)&sX[tile * 64 + lane];
                h4 w1 = *(volatile const h4*)&sW[(tile * 3 + 0) * 64 + lane];
                h4 w2 = *(volatile const h4*)&sW[(tile * 3 + 1) * 64 + lane];
                h4 w3 = *(volatile const h4*)&sW[(tile * 3 + 2) * 64 + lane];
                f4 a = MFMA16(ax, bext, z4);
                a = MFMA16(Aw0[gi][dq], hB[0], a);
                a = MFMA16(w1, hB[1], a);
                a = MFMA16(w2, hB[2], a);
                a = MFMA16(w3, hB[3], a);
                acc[gi] = a;
            }
            // paired-rcp activations (R10 verbatim): 5 exp2 + 1 rcp per unit
            h4 hv;
            #pragma unroll
            for (int rp = 0; rp < 2; ++rp) {
                const int r0 = rp * 2, r1 = r0 + 1;
                float EiA = EXP2(-acc[0][r0]);
                float EfA = EXP2(-acc[1][r0]);
                float EgA = EXP2( acc[2][r0]);
                float EoA = EXP2(-acc[3][r0]);
                float EiB = EXP2(-acc[0][r1]);
                float EfB = EXP2(-acc[1][r1]);
                float EgB = EXP2( acc[2][r1]);
                float EoB = EXP2(-acc[3][r1]);
                float piA = 1.0f + EiA, pfA = 1.0f + EfA;
                float pgA = 1.0f + EgA, poA = 1.0f + EoA;
                float piB = 1.0f + EiB, pfB = 1.0f + EfB;
                float pgB = 1.0f + EgB, poB = 1.0f + EoB;
                float t1A = piA * pgA,  t1B = piB * pgB;
                float DA  = pfA * t1A,  DB  = pfB * t1B;
                float vA  = fmaf(EgA, pfA, -pfA) * LOG2E2;
                float vB  = fmaf(EgB, pfB, -pfB) * LOG2E2;
                float numA = fmaf(c[dq][r0], t1A, vA);
                float numB = fmaf(c[dq][r1], t1B, vB);
                float R   = RCP(DA * DB);
                float cnA = fminf(numA * (R * DB), 40.0f);
                float cnB = fminf(numB * (R * DA), 40.0f);
                c[dq][r0] = cnA;
                c[dq][r1] = cnB;
                float EcA = EXP2(cnA), EcB = EXP2(cnB);
                float DhA = fmaf(poA, EcA, poA);
                float DhB = fmaf(poB, EcB, poB);
                float R2  = RCP(DhA * DhB);
                float rhA = R2 * DhB,  rhB = R2 * DhA;
                hv[r0] = (_Float16)fmaf(EcA, rhA, -rhA);
                hv[r1] = (_Float16)fmaf(EcB, rhB, -rhB);
            }
            hN[dq] = hv;
        }
        #pragma unroll
        for (int dq = 0; dq < 4; ++dq) hB[dq] = hN[dq];
    }

    // ---- epilogue: all waves done with sXT -> reuse it for final h
    __syncthreads();
    _Float16* sF = (_Float16*)sXT;
    #pragma unroll
    for (int dq = 0; dq < 4; ++dq)
        *(h4*)(sF + (wave * 16 + col) * FSTRIDE + dq * 16 + quad * 4) = hB[dq];
    // wave-local readback (rows of this wave only): no further barrier needed

    if (lane < 48) {
        const int sl = lane / 3;   // sequence within this wave's 16
        const int nc = lane % 3;   // class
        const _Float16* hp = sF + (wave * 16 + sl) * FSTRIDE;
        float a = b_fc[nc];
        #pragma unroll
        for (int u = 0; u < HID; ++u)
            a = fmaf((float)hp[u], W_fc[nc * HID + u], a);
        out[(size_t)(seqBase + wave * 16 + sl) * 3 + nc] = a;
    }
}

extern "C" void kernel_launch(void* const* d_in, const int* in_sizes, int n_in,
                              void* d_out, int out_size, void* d_ws, size_t ws_size,
                              hipStream_t stream) {
    const float* x    = (const float*)d_in[0];
    const float* W_ih = (const float*)d_in[1];
    const float* W_hh = (const float*)d_in[2];
    const float* b_ih = (const float*)d_in[3];
    const float* b_hh = (const float*)d_in[4];
    const float* W_fc = (const float*)d_in[5];
    const float* b_fc = (const float*)d_in[6];
    float* out = (float*)d_out;

    const int nSeq   = in_sizes[0] / SEQ_LEN;  // 512000
    const int blocks = nSeq / 64;              // 8000

    hipLaunchKernelGGL(lstm_fused, dim3(blocks), dim3(256), 0, stream,
                       x, W_ih, W_hh, b_ih, b_hh, W_fc, b_fc, out);
}

// Round 8
// 1993.991 us; speedup vs baseline: 2.9805x; 2.9805x over previous
//
#include <hip/hip_runtime.h>

typedef _Float16 h4 __attribute__((ext_vector_type(4)));
typedef float f4 __attribute__((ext_vector_type(4)));

#define SEQ_LEN 50
#define HID 64
#define FSTRIDE 68   // final-h LDS row pitch in halves

#if __has_builtin(__builtin_amdgcn_exp2f)
#define EXP2(x) __builtin_amdgcn_exp2f(x)
#else
extern "C" __device__ float __ocml_native_exp2_f32(float);
#define EXP2(x) __ocml_native_exp2_f32(x)
#endif
#define RCP(x) __builtin_amdgcn_rcpf(x)

// builtin x16 MFMA: compiled AND passed on this harness in R1/R3/R10.
// BUILTINS ONLY: R13's inline-asm MFMA NaN'd — the hazard recognizer cannot
// see operand roles inside INLINEASM, so VALU-write -> MFMA-SrcB edges went
// uncovered. Builtins keep all MFMA hazard management compiler-visible.
#define MFMA16(A,B,C) __builtin_amdgcn_mfma_f32_16x16x16f16(A, B, C, 0, 0, 0)

#define LOG2E  1.442695041f
#define LOG2E2 2.885390082f

// R14: barrier-free t-loop; weight residency made structural BOTH ways.
//
// Failure model from R10/R12/R13 (all one issue: 160 regs of loop-invariant
// fragments across a 50-iter loop):
//   R10: all-in-regs -> allocator spill, WRITE 200MB.
//   R12: regs+volatile-LDS -> compiler REMATERIALIZED the reg-chunk's global
//        loads inside the loop (VGPR dropped to 84, FETCH 6.6GB).
//   R13: asm-pinned AGPRs -> uncovered MFMA hazards, NaN.
// Fix:
//   (1) Only kc=0 chunk in regs (32 VGPRs), pinned by a zero-instruction
//       asm volatile("" : "+v") INSIDE the loop: per-iteration redefinition
//       makes it unrematerializable/unspillable-cheaply, yet fully visible
//       to the scheduler (no volatile, no asm MFMA).
//   (2) kc=1..3 + x-proj fragments in LDS, SHARED by 4 waves/block,
//       layout [tile][slot][lane] -> lane stride 8B = 2-way bank aliasing
//       (free, m136). Loads use an opaque per-iteration index
//       (asm("" : "+v"(ob))) so LICM cannot hoist them back into registers
//       (R12's pressure source); they stay plain C loads.
// Register audit: Aw0 32 + hB 8 + hN 8 + c 16 + acc 16 + frags 8 + temps
// ~30 + addr ~8 = ~142 < 168 cap at (256,3). LDS 44.8KB -> 3 blocks/CU ->
// 12 independent waves/CU, ZERO barriers in the t-loop.
//
// Structure (R10, HW-verified): one wave owns 16 seqs end-to-end.
// mfma_f32_16x16x16_f16 D-layout == B-layout, so the activated h4 of
// unit-quarter dq IS the B-fragment for k-chunk dq of the next step.
// x-projection via x16 MFMA (A nonzero only quad0 k=0,1; C=0) — verified
// in R1/R3/R10.
//
// Activation math (R6/R7, verified): pre-acts pre-scaled (i,f,o: log2e;
// g: 2log2e, folded into fragments). Cell kept in 2log2e domain. Paired
// rcp both sites. c' clamp 40 keeps paired products finite
// (tanh(40/2L2) = 1-2e-12 == fp32 1.0: no output change).
__global__ __launch_bounds__(256, 3)
void lstm_fused(const float* __restrict__ x,
                const float* __restrict__ W_ih,
                const float* __restrict__ W_hh,
                const float* __restrict__ b_ih,
                const float* __restrict__ b_hh,
                const float* __restrict__ W_fc,
                const float* __restrict__ b_fc,
                float* __restrict__ out)
{
    // sW[tile][slot][lane]: slot 0..2 = W_hh k-chunks 1..3; slot 3 = x-proj.
    __shared__ h4    sW[16 * 4 * 64];       // 32 KB
    __shared__ float sXT[SEQ_LEN * 64];     // 12.8 KB; reused as sF after loop

    const int tid  = threadIdx.x;
    const int wave = tid >> 6;
    const int lane = tid & 63;
    const int col  = lane & 15;
    const int quad = lane >> 4;
    const int seqBase = blockIdx.x << 6;    // 64 sequences per block

    // ---- stage x transposed
    for (int i = tid; i < SEQ_LEN * 64; i += 256) {
        const int s = i / SEQ_LEN;
        const int t = i - s * SEQ_LEN;
        sXT[t * 64 + s] = x[(size_t)(seqBase + s) * SEQ_LEN + t];
    }

    // ---- stage shared weight fragments (pre-scaled; i,f,o: log2e, g: 2log2e)
    for (int i = tid; i < 16 * 4 * 64; i += 256) {
        const int ln   = i & 63;
        const int slot = (i >> 6) & 3;
        const int tile = i >> 8;
        const int gi = tile >> 2, dq = tile & 3;
        const int cl = ln & 15, qd = ln >> 4;
        const int n  = gi * 64 + dq * 16 + cl;
        const float scale = (gi == 2) ? LOG2E2 : LOG2E;
        h4 a = {};
        if (slot < 3) {
            const float* wp = W_hh + (size_t)n * HID + (slot + 1) * 16 + qd * 4;
            f4 w = *(const f4*)wp;
            a[0] = (_Float16)(w[0] * scale);
            a[1] = (_Float16)(w[1] * scale);
            a[2] = (_Float16)(w[2] * scale);
            a[3] = (_Float16)(w[3] * scale);
        } else if (qd == 0) {
            a[0] = (_Float16)(W_ih[n] * scale);
            a[1] = (_Float16)((b_ih[n] + b_hh[n]) * scale);
        }
        sW[(tile * 4 + slot) * 64 + ln] = a;
    }

    // ---- kc=0 weight chunk resident in registers (32 VGPRs)
    h4 Aw0[4][4];
    #pragma unroll
    for (int gi = 0; gi < 4; ++gi) {
        const float scale = (gi == 2) ? LOG2E2 : LOG2E;
        #pragma unroll
        for (int dq = 0; dq < 4; ++dq) {
            const int n = gi * 64 + dq * 16 + col;
            const float* wp = W_hh + (size_t)n * HID + quad * 4;
            f4 w = *(const f4*)wp;
            h4 a;
            a[0] = (_Float16)(w[0] * scale);
            a[1] = (_Float16)(w[1] * scale);
            a[2] = (_Float16)(w[2] * scale);
            a[3] = (_Float16)(w[3] * scale);
            Aw0[gi][dq] = a;
        }
    }

    const f4 z4 = {0.0f, 0.0f, 0.0f, 0.0f};

    h4 hB[4] = {};          // h as ready-made B-fragments (h0 = 0)
    float c[4][4];
    #pragma unroll
    for (int dq = 0; dq < 4; ++dq)
        #pragma unroll
        for (int r = 0; r < 4; ++r) c[dq][r] = 0.0f;

    __syncthreads();        // staging visible to all waves; LAST barrier
                            // before the epilogue — t-loop is barrier-free.

    #pragma clang loop unroll(disable)
    for (int t = 0; t < SEQ_LEN; ++t) {
        // pin Aw0 in-loop: zero-instruction redefinition blocks remat/spill
        #pragma unroll
        for (int gi = 0; gi < 4; ++gi)
            #pragma unroll
            for (int dq = 0; dq < 4; ++dq)
                asm volatile("" : "+v"(Aw0[gi][dq]));
        // opaque lane index: LDS frag loads can't be hoisted out of the loop
        int ob = lane;
        asm volatile("" : "+v"(ob));

        const float xt = sXT[t * 64 + wave * 16 + col];
        h4 bext = {};
        bext[0] = (_Float16)xt;
        bext[1] = (_Float16)1.0f;

        h4 hN[4];
        #pragma unroll
        for (int dq = 0; dq < 4; ++dq) {
            f4 acc[4];
            #pragma unroll
            for (int gi = 0; gi < 4; ++gi) {
                const int tb = (gi * 4 + dq) * 256;   // tile base in h4 units
                h4 ax = sW[tb + 3 * 64 + ob];
                h4 w1 = sW[tb + 0 * 64 + ob];
                h4 w2 = sW[tb + 1 * 64 + ob];
                h4 w3 = sW[tb + 2 * 64 + ob];
                f4 a = MFMA16(ax, bext, z4);          // x-term + bias, C=0
                a = MFMA16(Aw0[gi][dq], hB[0], a);
                a = MFMA16(w1, hB[1], a);
                a = MFMA16(w2, hB[2], a);
                a = MFMA16(w3, hB[3], a);
                acc[gi] = a;
            }
            // paired-rcp activations (R10 verbatim): 5 exp2 + 1 rcp / unit
            h4 hv;
            #pragma unroll
            for (int rp = 0; rp < 2; ++rp) {
                const int r0 = rp * 2, r1 = r0 + 1;
                float EiA = EXP2(-acc[0][r0]);
                float EfA = EXP2(-acc[1][r0]);
                float EgA = EXP2( acc[2][r0]);
                float EoA = EXP2(-acc[3][r0]);
                float EiB = EXP2(-acc[0][r1]);
                float EfB = EXP2(-acc[1][r1]);
                float EgB = EXP2( acc[2][r1]);
                float EoB = EXP2(-acc[3][r1]);
                float piA = 1.0f + EiA, pfA = 1.0f + EfA;
                float pgA = 1.0f + EgA, poA = 1.0f + EoA;
                float piB = 1.0f + EiB, pfB = 1.0f + EfB;
                float pgB = 1.0f + EgB, poB = 1.0f + EoB;
                float t1A = piA * pgA,  t1B = piB * pgB;
                float DA  = pfA * t1A,  DB  = pfB * t1B;
                float vA  = fmaf(EgA, pfA, -pfA) * LOG2E2;
                float vB  = fmaf(EgB, pfB, -pfB) * LOG2E2;
                float numA = fmaf(c[dq][r0], t1A, vA);
                float numB = fmaf(c[dq][r1], t1B, vB);
                float R   = RCP(DA * DB);
                float cnA = fminf(numA * (R * DB), 40.0f);
                float cnB = fminf(numB * (R * DA), 40.0f);
                c[dq][r0] = cnA;
                c[dq][r1] = cnB;
                float EcA = EXP2(cnA), EcB = EXP2(cnB);
                float DhA = fmaf(poA, EcA, poA);
                float DhB = fmaf(poB, EcB, poB);
                float R2  = RCP(DhA * DhB);
                float rhA = R2 * DhB,  rhB = R2 * DhA;
                hv[r0] = (_Float16)fmaf(EcA, rhA, -rhA);
                hv[r1] = (_Float16)fmaf(EcB, rhB, -rhB);
            }
            hN[dq] = hv;
        }
        #pragma unroll
        for (int dq = 0; dq < 4; ++dq) hB[dq] = hN[dq];
    }

    // ---- epilogue: reuse sXT as final-h buffer. Barrier required: waves
    // progress independently, and another wave may still be reading its x.
    __syncthreads();
    _Float16* sF = (_Float16*)sXT;
    #pragma unroll
    for (int dq = 0; dq < 4; ++dq)
        *(h4*)(sF + (wave * 16 + col) * FSTRIDE + dq * 16 + quad * 4) = hB[dq];
    // FC readback is wave-local (own 16 rows): no further barrier needed.

    if (lane < 48) {
        const int sl = lane / 3;   // sequence within this wave's 16
        const int nc = lane % 3;   // class
        const _Float16* hp = sF + (wave * 16 + sl) * FSTRIDE;
        float a = b_fc[nc];
        #pragma unroll
        for (int u = 0; u < HID; ++u)
            a = fmaf((float)hp[u], W_fc[nc * HID + u], a);
        out[(size_t)(seqBase + wave * 16 + sl) * 3 + nc] = a;
    }
}

extern "C" void kernel_launch(void* const* d_in, const int* in_sizes, int n_in,
                              void* d_out, int out_size, void* d_ws, size_t ws_size,
                              hipStream_t stream) {
    const float* x    = (const float*)d_in[0];
    const float* W_ih = (const float*)d_in[1];
    const float* W_hh = (const float*)d_in[2];
    const float* b_ih = (const float*)d_in[3];
    const float* b_hh = (const float*)d_in[4];
    const float* W_fc = (const float*)d_in[5];
    const float* b_fc = (const float*)d_in[6];
    float* out = (float*)d_out;

    const int nSeq   = in_sizes[0] / SEQ_LEN;  // 512000
    const int blocks = nSeq / 64;              // 8000

    hipLaunchKernelGGL(lstm_fused, dim3(blocks), dim3(256), 0, stream,
                       x, W_ih, W_hh, b_ih, b_hh, W_fc, b_fc, out);
}